// Round 1
// baseline (560.429 us; speedup 1.0000x reference)
//
#include <hip/hip_runtime.h>

#define BB 2
#define LL 512
#define HH 128
#define NH 8

// K1: q = x@Wq+bq ; kp = x@Wk+bk+abs_pos_k ; vp = x@Wv+bv+abs_pos_v
// 4 rows per block, 128 threads (one output column each).
__global__ __launch_bounds__(128) void qkv_proj_kernel(
    const float* __restrict__ x,
    const float* __restrict__ abs_pos_k,
    const float* __restrict__ abs_pos_v,
    const float* __restrict__ Wq, const float* __restrict__ bq,
    const float* __restrict__ Wk, const float* __restrict__ bk,
    const float* __restrict__ Wv, const float* __restrict__ bv,
    float* __restrict__ q, float* __restrict__ kp, float* __restrict__ vp)
{
    const int r0 = blockIdx.x * 4;
    const int c = threadIdx.x;
    __shared__ float xs[4][HH];
    #pragma unroll
    for (int r = 0; r < 4; ++r) xs[r][c] = x[(r0 + r) * HH + c];
    __syncthreads();
    float aq[4], ak[4], av[4];
    #pragma unroll
    for (int r = 0; r < 4; ++r) { aq[r] = bq[c]; ak[r] = bk[c]; av[r] = bv[c]; }
    for (int i = 0; i < HH; ++i) {
        const float wq = Wq[i * HH + c];
        const float wk = Wk[i * HH + c];
        const float wv = Wv[i * HH + c];
        #pragma unroll
        for (int r = 0; r < 4; ++r) {
            const float xv = xs[r][i];
            aq[r] = fmaf(xv, wq, aq[r]);
            ak[r] = fmaf(xv, wk, ak[r]);
            av[r] = fmaf(xv, wv, av[r]);
        }
    }
    #pragma unroll
    for (int r = 0; r < 4; ++r) {
        const int idx = (r0 + r) * HH + c;
        q[idx]  = aq[r];
        kp[idx] = ak[r] + abs_pos_k[idx];
        vp[idx] = av[r] + abs_pos_v[idx];
    }
}

// K2: fully fused attention. One block per (b, qi). 256 threads:
//   t = kis*32 + c4 ; kis = ki sub-row (0..7), c4 = float4 index over H (0..31)
//   head h = c4>>2 (each head spans 4 float4s = 16 floats).
// Streams time_k slice (256 KB) then time_v slice (256 KB) exactly once.
__global__ __launch_bounds__(256) void attn_fused_kernel(
    const float* __restrict__ q,
    const float* __restrict__ kp,
    const float* __restrict__ vp,
    const float* __restrict__ time_k,
    const float* __restrict__ time_v,
    const float* __restrict__ mask,
    const float* __restrict__ Wo,
    const float* __restrict__ bo,
    float* __restrict__ out)
{
    const int blk = blockIdx.x;
    const int b   = blk >> 9;          // / LL
    const int qi  = blk & (LL - 1);
    const int t   = threadIdx.x;
    const int c4  = t & 31;
    const int kis = t >> 5;
    const int h   = c4 >> 2;

    __shared__ float s_p[NH][LL];      // scores -> probs, 16 KB
    __shared__ float s_q[HH];
    __shared__ float s_red[8][HH];     // ctx partial sums, 4 KB
    __shared__ float s_ctx[HH];
    __shared__ float s_inv[NH];

    if (t < HH) s_q[t] = q[(b * LL + qi) * HH + t];
    __syncthreads();

    const float4 q4 = ((const float4*)s_q)[c4];
    const float4* __restrict__ tk4 = (const float4*)(time_k + (size_t)(b * LL + qi) * (size_t)(LL * HH));
    const float4* __restrict__ kq4 = (const float4*)(kp + (size_t)b * (size_t)(LL * HH));
    const float*  __restrict__ mrow = mask + (size_t)(b * LL + qi) * LL;

    // ---- scores: s[h][ki] = (q . (k' + tk)) / 4 + mask ----
    #pragma unroll 4
    for (int kb = 0; kb < LL / 8; ++kb) {
        const int ki = kb * 8 + kis;
        const float4 a  = tk4[ki * 32 + c4];
        const float4 bk = kq4[ki * 32 + c4];
        float part = q4.x * (a.x + bk.x) + q4.y * (a.y + bk.y)
                   + q4.z * (a.z + bk.z) + q4.w * (a.w + bk.w);
        part += __shfl_xor(part, 1);
        part += __shfl_xor(part, 2);
        if ((c4 & 3) == 0)
            s_p[h][ki] = part * 0.25f + mrow[ki];
    }
    __syncthreads();

    // ---- softmax per head row: 32 threads per head ----
    {
        const int hh  = t >> 5;
        const int l32 = t & 31;
        float m = -1e30f;
        #pragma unroll
        for (int j = 0; j < LL / 32; ++j) m = fmaxf(m, s_p[hh][l32 + j * 32]);
        #pragma unroll
        for (int off = 16; off; off >>= 1) m = fmaxf(m, __shfl_xor(m, off));
        float sum = 0.f;
        #pragma unroll
        for (int j = 0; j < LL / 32; ++j) {
            const float e = __expf(s_p[hh][l32 + j * 32] - m);
            s_p[hh][l32 + j * 32] = e;
            sum += e;
        }
        #pragma unroll
        for (int off = 16; off; off >>= 1) sum += __shfl_xor(sum, off);
        if (l32 == 0) s_inv[hh] = 1.0f / sum;
    }
    __syncthreads();

    // ---- ctx[h*16+d] = (1/sum_h) * sum_ki e[h][ki] * (v'[ki] + tv[ki]) ----
    const float4* __restrict__ tv4 = (const float4*)(time_v + (size_t)(b * LL + qi) * (size_t)(LL * HH));
    const float4* __restrict__ vq4 = (const float4*)(vp + (size_t)b * (size_t)(LL * HH));
    float4 acc = make_float4(0.f, 0.f, 0.f, 0.f);
    #pragma unroll 4
    for (int kb = 0; kb < LL / 8; ++kb) {
        const int ki = kb * 8 + kis;
        const float p = s_p[h][ki];
        const float4 a  = tv4[ki * 32 + c4];
        const float4 bv = vq4[ki * 32 + c4];
        acc.x = fmaf(p, a.x + bv.x, acc.x);
        acc.y = fmaf(p, a.y + bv.y, acc.y);
        acc.z = fmaf(p, a.z + bv.z, acc.z);
        acc.w = fmaf(p, a.w + bv.w, acc.w);
    }
    const float inv = s_inv[h];
    ((float4*)s_red)[kis * 32 + c4] = make_float4(acc.x * inv, acc.y * inv, acc.z * inv, acc.w * inv);
    __syncthreads();

    if (t < HH) {
        float cv = 0.f;
        #pragma unroll
        for (int r = 0; r < 8; ++r) cv += s_red[r][t];
        s_ctx[t] = cv;
    }
    __syncthreads();

    // ---- out = ctx @ Wo + bo ----
    if (t < HH) {
        float o = bo[t];
        for (int i = 0; i < HH; ++i) o = fmaf(s_ctx[i], Wo[i * HH + t], o);
        out[(b * LL + qi) * HH + t] = o;
    }
}

extern "C" void kernel_launch(void* const* d_in, const int* in_sizes, int n_in,
                              void* d_out, int out_size, void* d_ws, size_t ws_size,
                              hipStream_t stream) {
    const float* x         = (const float*)d_in[0];
    const float* time_k    = (const float*)d_in[1];
    const float* time_v    = (const float*)d_in[2];
    const float* abs_pos_k = (const float*)d_in[3];
    const float* abs_pos_v = (const float*)d_in[4];
    const float* attn_mask = (const float*)d_in[5];
    const float* Wq = (const float*)d_in[6];
    const float* bq = (const float*)d_in[7];
    const float* Wk = (const float*)d_in[8];
    const float* bk = (const float*)d_in[9];
    const float* Wv = (const float*)d_in[10];
    const float* bv = (const float*)d_in[11];
    const float* Wo = (const float*)d_in[12];
    const float* bo = (const float*)d_in[13];
    float* out = (float*)d_out;

    float* q  = (float*)d_ws;              // [2*512*128]
    float* kp = q  + BB * LL * HH;         // k + abs_k
    float* vp = kp + BB * LL * HH;         // v + abs_v

    qkv_proj_kernel<<<BB * LL / 4, 128, 0, stream>>>(
        x, abs_pos_k, abs_pos_v, Wq, bq, Wk, bk, Wv, bv, q, kp, vp);

    attn_fused_kernel<<<BB * LL, 256, 0, stream>>>(
        q, kp, vp, time_k, time_v, attn_mask, Wo, bo, out);
}

// Round 2
// 546.942 us; speedup vs baseline: 1.0247x; 1.0247x over previous
//
#include <hip/hip_runtime.h>

#define BB 2
#define LL 512
#define HH 128
#define NH 8
#define SP_STRIDE 9   // pad 8 heads to 9 -> odd stride, conflict-free in all phases

// K1: q = x@Wq+bq ; kp = x@Wk+bk+abs_pos_k ; vp = x@Wv+bv+abs_pos_v
__global__ __launch_bounds__(128) void qkv_proj_kernel(
    const float* __restrict__ x,
    const float* __restrict__ abs_pos_k,
    const float* __restrict__ abs_pos_v,
    const float* __restrict__ Wq, const float* __restrict__ bq,
    const float* __restrict__ Wk, const float* __restrict__ bk,
    const float* __restrict__ Wv, const float* __restrict__ bv,
    float* __restrict__ q, float* __restrict__ kp, float* __restrict__ vp)
{
    const int r0 = blockIdx.x * 4;
    const int c = threadIdx.x;
    __shared__ float xs[4][HH];
    #pragma unroll
    for (int r = 0; r < 4; ++r) xs[r][c] = x[(r0 + r) * HH + c];
    __syncthreads();
    float aq[4], ak[4], av[4];
    #pragma unroll
    for (int r = 0; r < 4; ++r) { aq[r] = bq[c]; ak[r] = bk[c]; av[r] = bv[c]; }
    #pragma unroll 4
    for (int i = 0; i < HH; ++i) {
        const float wq = Wq[i * HH + c];
        const float wk = Wk[i * HH + c];
        const float wv = Wv[i * HH + c];
        #pragma unroll
        for (int r = 0; r < 4; ++r) {
            const float xv = xs[r][i];
            aq[r] = fmaf(xv, wq, aq[r]);
            ak[r] = fmaf(xv, wk, ak[r]);
            av[r] = fmaf(xv, wv, av[r]);
        }
    }
    #pragma unroll
    for (int r = 0; r < 4; ++r) {
        const int idx = (r0 + r) * HH + c;
        q[idx]  = aq[r];
        kp[idx] = ak[r] + abs_pos_k[idx];
        vp[idx] = av[r] + abs_pos_v[idx];
    }
}

// K2: fully fused attention. One block per (b, qi). 256 threads:
//   t = kis*32 + c4 ; kis = ki sub-row (0..7), c4 = float4 index over H (0..31)
//   head h = c4>>2 (each head spans 4 float4s = 16 floats).
__global__ __launch_bounds__(256) void attn_fused_kernel(
    const float* __restrict__ q,
    const float* __restrict__ kp,
    const float* __restrict__ vp,
    const float* __restrict__ time_k,
    const float* __restrict__ time_v,
    const float* __restrict__ mask,
    const float* __restrict__ Wo,
    const float* __restrict__ bo,
    float* __restrict__ out)
{
    const int blk = blockIdx.x;
    const int b   = blk >> 9;          // / LL
    const int qi  = blk & (LL - 1);
    const int t   = threadIdx.x;
    const int c4  = t & 31;
    const int kis = t >> 5;
    const int h   = c4 >> 2;

    __shared__ float s_p[LL * SP_STRIDE];  // scores->probs, [ki][h] pad 9, 18.4 KB
    __shared__ float s_q[HH];
    __shared__ float s_red[8][HH];         // ctx partials, then out-proj partials
    __shared__ float s_ctx[HH];
    __shared__ float s_inv[NH];

    if (t < HH) s_q[t] = q[(b * LL + qi) * HH + t];
    __syncthreads();

    const float4 q4 = ((const float4*)s_q)[c4];
    const float4* __restrict__ tk4 = (const float4*)(time_k + (size_t)(b * LL + qi) * (size_t)(LL * HH));
    const float4* __restrict__ kq4 = (const float4*)(kp + (size_t)b * (size_t)(LL * HH));
    const float*  __restrict__ mrow = mask + (size_t)(b * LL + qi) * LL;

    // ---- phase 1: raw scores s_p[ki][h] = q . (k' + tk)   (no mask, no scale here)
    #pragma unroll 8
    for (int kb = 0; kb < LL / 8; ++kb) {
        const int ki = kb * 8 + kis;
        const float4 a  = tk4[ki * 32 + c4];
        const float4 bk = kq4[ki * 32 + c4];
        float part = q4.x * (a.x + bk.x) + q4.y * (a.y + bk.y)
                   + q4.z * (a.z + bk.z) + q4.w * (a.w + bk.w);
        part += __shfl_xor(part, 1);
        part += __shfl_xor(part, 2);
        if ((c4 & 3) == 0)
            s_p[ki * SP_STRIDE + h] = part;
    }
    __syncthreads();

    // ---- phase 2: softmax per head row (32 threads per head); scale+mask here
    {
        const int hh  = t >> 5;
        const int l32 = t & 31;
        float v[LL / 32];
        float m = -1e30f;
        #pragma unroll
        for (int j = 0; j < LL / 32; ++j) {
            const int ki = l32 + j * 32;
            v[j] = s_p[ki * SP_STRIDE + hh] * 0.25f + mrow[ki];
            m = fmaxf(m, v[j]);
        }
        #pragma unroll
        for (int off = 16; off; off >>= 1) m = fmaxf(m, __shfl_xor(m, off));
        float sum = 0.f;
        #pragma unroll
        for (int j = 0; j < LL / 32; ++j) {
            const float e = __expf(v[j] - m);
            s_p[(l32 + j * 32) * SP_STRIDE + hh] = e;
            sum += e;
        }
        #pragma unroll
        for (int off = 16; off; off >>= 1) sum += __shfl_xor(sum, off);
        if (l32 == 0) s_inv[hh] = 1.0f / sum;
    }
    __syncthreads();

    // ---- phase 3: ctx = (1/sum_h) * sum_ki e[ki][h] * (v'[ki] + tv[ki])
    const float4* __restrict__ tv4 = (const float4*)(time_v + (size_t)(b * LL + qi) * (size_t)(LL * HH));
    const float4* __restrict__ vq4 = (const float4*)(vp + (size_t)b * (size_t)(LL * HH));
    float4 acc = make_float4(0.f, 0.f, 0.f, 0.f);
    #pragma unroll 8
    for (int kb = 0; kb < LL / 8; ++kb) {
        const int ki = kb * 8 + kis;
        const float p = s_p[ki * SP_STRIDE + h];
        const float4 a  = tv4[ki * 32 + c4];
        const float4 bv = vq4[ki * 32 + c4];
        acc.x = fmaf(p, a.x + bv.x, acc.x);
        acc.y = fmaf(p, a.y + bv.y, acc.y);
        acc.z = fmaf(p, a.z + bv.z, acc.z);
        acc.w = fmaf(p, a.w + bv.w, acc.w);
    }
    const float inv = s_inv[h];
    ((float4*)s_red)[kis * 32 + c4] = make_float4(acc.x * inv, acc.y * inv, acc.z * inv, acc.w * inv);
    __syncthreads();

    if (t < HH) {
        float cv = 0.f;
        #pragma unroll
        for (int r = 0; r < 8; ++r) cv += s_red[r][t];
        s_ctx[t] = cv;
    }
    __syncthreads();

    // ---- phase 4: out = ctx @ Wo + bo, split i-range across the two half-blocks
    {
        const int to   = t & (HH - 1);
        const int half = t >> 7;
        float o = half ? 0.f : bo[to];
        const int i0 = half * (HH / 2);
        #pragma unroll 4
        for (int i = i0; i < i0 + HH / 2; ++i)
            o = fmaf(s_ctx[i], Wo[i * HH + to], o);
        __syncthreads();                 // s_red reads above are done; safe to reuse
        s_red[half][to] = o;
    }
    __syncthreads();
    if (t < HH)
        out[(b * LL + qi) * HH + t] = s_red[0][t] + s_red[1][t];
}

extern "C" void kernel_launch(void* const* d_in, const int* in_sizes, int n_in,
                              void* d_out, int out_size, void* d_ws, size_t ws_size,
                              hipStream_t stream) {
    const float* x         = (const float*)d_in[0];
    const float* time_k    = (const float*)d_in[1];
    const float* time_v    = (const float*)d_in[2];
    const float* abs_pos_k = (const float*)d_in[3];
    const float* abs_pos_v = (const float*)d_in[4];
    const float* attn_mask = (const float*)d_in[5];
    const float* Wq = (const float*)d_in[6];
    const float* bq = (const float*)d_in[7];
    const float* Wk = (const float*)d_in[8];
    const float* bk = (const float*)d_in[9];
    const float* Wv = (const float*)d_in[10];
    const float* bv = (const float*)d_in[11];
    const float* Wo = (const float*)d_in[12];
    const float* bo = (const float*)d_in[13];
    float* out = (float*)d_out;

    float* q  = (float*)d_ws;              // [2*512*128]
    float* kp = q  + BB * LL * HH;         // k + abs_k
    float* vp = kp + BB * LL * HH;         // v + abs_v

    qkv_proj_kernel<<<BB * LL / 4, 128, 0, stream>>>(
        x, abs_pos_k, abs_pos_v, Wq, bq, Wk, bk, Wv, bv, q, kp, vp);

    attn_fused_kernel<<<BB * LL, 256, 0, stream>>>(
        q, kp, vp, time_k, time_v, attn_mask, Wo, bo, out);
}